// Round 5
// baseline (103.615 us; speedup 1.0000x reference)
//
#include <hip/hip_runtime.h>

typedef float f2 __attribute__((ext_vector_type(2)));
typedef _Float16 half_t;
typedef _Float16 h4 __attribute__((ext_vector_type(4)));
typedef _Float16 h8 __attribute__((ext_vector_type(8)));

// Compile-time filter constants (fold to literals).
static constexpr float REC_LO[12] = {
  0.11154074335008017f, 0.4946238903983854f, 0.7511339080215775f, 0.3152503517092432f,
  -0.22626469396516913f, -0.12976686756709563f, 0.09750160558707936f, 0.02752286553001629f,
  -0.031582039318031156f, 0.0005538422009938016f, 0.004777257511010651f, -0.00107730108499558f };
static constexpr float REC_HI[12] = {
  -0.00107730108499558f, -0.004777257511010651f, 0.0005538422009938016f, 0.031582039318031156f,
  0.02752286553001629f, -0.09750160558707936f, -0.12976686756709563f, 0.22626469396516913f,
  0.3152503517092432f, -0.7511339080215775f, 0.4946238903983854f, -0.11154074335008017f };
static constexpr float DEC_LO[12] = {
  -0.00107730108499558f, 0.004777257511010651f, 0.0005538422009938016f, -0.031582039318031156f,
  0.02752286553001629f, 0.09750160558707936f, -0.12976686756709563f, -0.22626469396516913f,
  0.3152503517092432f, 0.7511339080215775f, 0.4946238903983854f, 0.11154074335008017f };
static constexpr float DEC_HI[12] = {
  -0.11154074335008017f, 0.4946238903983854f, -0.7511339080215775f, 0.3152503517092432f,
  0.22626469396516913f, -0.12976686756709563f, -0.09750160558707936f, 0.02752286553001629f,
  0.031582039318031156f, 0.0005538422009938016f, -0.004777257511010651f, -0.00107730108499558f };

#define NROWS 16384
#define WPB 4  // waves (= rows) per block

// ws layout in HALF elements, per-row strides padded to x8 for 16B alignment:
//  hi0 520@0, hi1 264@520, hi2 144@784, hi3 80@928, hi4 48@1008, hi5 32@1056,
//  hi6 24@1088, hi7 16@1112, loFinal 16@1128, hm 16@1144, loMixed 16@1160.
//  Total 1176 halves/row = 38.5 MB.

// ---------------- Fused 8-level analysis: one WAVE per row ----------------
// Level 0 reads x directly from global (8-wide chunks, edge reflection built
// from clamped loads with compile-time index maps). Levels 1..7 via LDS.
__global__ __launch_bounds__(256) void afb_fused(const float* __restrict__ x,
                                                 half_t* __restrict__ ws) {
  __shared__ float sA[WPB][548];  // origin 14: lo1 (517) + pads
  __shared__ float sB[WPB][296];  // origin 14: lo2 (264) + pads
  constexpr int LENS[9] = {1024, 517, 264, 137, 74, 42, 26, 18, 14};
  constexpr int HSTR[8] = {520, 264, 144, 80, 48, 32, 24, 16};
  constexpr int HOFF[8] = {0, 520, 784, 928, 1008, 1056, 1088, 1112};
  const int wid = threadIdx.x >> 6;
  const int lane = threadIdx.x & 63;
  const int row = blockIdx.x * WPB + wid;
  float* bufA = sA[wid];
  float* bufB = sB[wid];

  const float* xrow = x + (size_t)row * 1024;
  half_t* hi0 = ws + (size_t)row * 520;

  // ---- Level 0: 65 chunks of 8 outputs (chunk 64 has 5 valid) ----
#pragma unroll
  for (int it = 0; it < 2; ++it) {
    int q = it * 64 + lane;
    if (q < 65) {
      int base = (q == 0) ? 0 : ((q == 64) ? 996 : 16 * q - 12);
      float xv[28];
#pragma unroll
      for (int r = 0; r < 7; ++r) {
        float4 v = *reinterpret_cast<const float4*>(xrow + base + 4 * r);
        xv[4 * r] = v.x; xv[4 * r + 1] = v.y; xv[4 * r + 2] = v.z; xv[4 * r + 3] = v.w;
      }
      // window w[e] = x_sym[16q - 10 + e], e in [0,26)
      float w[26];
      if (q == 0) {
#pragma unroll
        for (int e = 0; e < 26; ++e) w[e] = xv[e < 10 ? 9 - e : e - 10];
      } else if (q == 64) {
#pragma unroll
        for (int e = 0; e < 26; ++e) w[e] = (e < 10) ? xv[18 + e] : ((e < 20) ? xv[37 - e] : 0.f);
      } else {
#pragma unroll
        for (int e = 0; e < 26; ++e) w[e] = xv[2 + e];
      }
      f2 a[8];
#pragma unroll
      for (int d = 0; d < 8; ++d) a[d] = (f2){0.f, 0.f};
#pragma unroll
      for (int k = 0; k < 12; ++k) {
        f2 c = (f2){REC_LO[k], REC_HI[k]};
#pragma unroll
        for (int d = 0; d < 8; ++d) a[d] += w[2 * d + k] * c;
      }
      if (q < 64) {
#pragma unroll
        for (int d = 0; d < 4; ++d)
          *reinterpret_cast<f2*>(bufA + 14 + 8 * q + 2 * d) = (f2){a[2 * d].x, a[2 * d + 1].x};
        h8 hh;
#pragma unroll
        for (int d = 0; d < 8; ++d) hh[d] = (half_t)a[d].y;
        *reinterpret_cast<h8*>(hi0 + 8 * q) = hh;
      } else {  // outputs 512..516
#pragma unroll
        for (int d = 0; d < 5; ++d) {
          bufA[14 + 512 + d] = a[d].x;
          hi0[512 + d] = (half_t)a[d].y;
        }
      }
    }
  }
  // symmetric pads for level 1 (same-wave LDS ordering)
  if (lane < 10) bufA[13 - lane] = bufA[14 + lane];
  if (lane < 11) bufA[14 + 517 + lane] = bufA[14 + 516 - lane];

  float* cur = bufA;
  float* dst = bufB;
#pragma unroll
  for (int j = 1; j < 8; ++j) {
    const int outN = LENS[j + 1];
    const int NCH = (outN + 3) / 4;
    half_t* hiRow = ws + (size_t)NROWS * HOFF[j] + (size_t)row * HSTR[j];
#pragma unroll
    for (int q0 = 0; q0 < NCH; q0 += 64) {
      int q = q0 + lane;
      if (q < NCH) {
        const float* pp = cur + 8 * q + 4;  // padded idx of tap 0 for n0 = 4q
        float xv[20];
#pragma unroll
        for (int r = 0; r < 5; ++r) {
          float4 v = *reinterpret_cast<const float4*>(pp + 4 * r);
          xv[4 * r] = v.x; xv[4 * r + 1] = v.y; xv[4 * r + 2] = v.z; xv[4 * r + 3] = v.w;
        }
        f2 a0 = {0.f, 0.f}, a1 = {0.f, 0.f}, a2 = {0.f, 0.f}, a3 = {0.f, 0.f};
#pragma unroll
        for (int k = 0; k < 12; ++k) {
          f2 c = (f2){REC_LO[k], REC_HI[k]};
          a0 += xv[k] * c; a1 += xv[2 + k] * c; a2 += xv[4 + k] * c; a3 += xv[6 + k] * c;
        }
        if (j < 7) {
          *reinterpret_cast<f2*>(dst + 14 + 4 * q) = (f2){a0.x, a1.x};
          *reinterpret_cast<f2*>(dst + 16 + 4 * q) = (f2){a2.x, a3.x};
        } else {  // final lo (14) -> fp16
          h4 hl; hl[0] = (half_t)a0.x; hl[1] = (half_t)a1.x; hl[2] = (half_t)a2.x; hl[3] = (half_t)a3.x;
          *reinterpret_cast<h4*>(ws + (size_t)NROWS * 1128 + (size_t)row * 16 + 4 * q) = hl;
        }
        h4 hh; hh[0] = (half_t)a0.y; hh[1] = (half_t)a1.y; hh[2] = (half_t)a2.y; hh[3] = (half_t)a3.y;
        *reinterpret_cast<h4*>(hiRow + 4 * q) = hh;
      }
    }
    if (j < 7) {
      if (lane < 10) dst[13 - lane] = dst[14 + lane];
      if (lane < 11) dst[14 + outN + lane] = dst[14 + outN - 1 - lane];
      float* t = cur; cur = dst; dst = t;
    }
  }
}

// ---------------- Fused 8-level synthesis: one WAVE per row ----------------
// 8-wide chunks (every level = 1 iteration; s7: 64 chunks exactly). hi is read
// directly from global fp16 inside the compute loop (no LDS staging).
__global__ __launch_bounds__(256) void sfb_fused(const half_t* __restrict__ ws,
                                                 float* __restrict__ out) {
  __shared__ float sP[WPB][280];  // y0,y2,y4,y6 (max 264) + slack
  __shared__ float sQ[WPB][536];  // y1,y3,y5,y7 (max 518) + slack
  constexpr int LENSY[8] = {14, 18, 26, 42, 74, 137, 264, 517};
  constexpr int HSOFF[8] = {1144, 1088, 1056, 1008, 928, 784, 520, 0};  // hm, hi6..hi0
  constexpr int HSSTR[8] = {16, 24, 32, 48, 80, 144, 264, 520};
  const int wid = threadIdx.x >> 6;
  const int lane = threadIdx.x & 63;
  const int row = blockIdx.x * WPB + wid;
  float* ping = sP[wid];
  float* pong = sQ[wid];

  if (lane < 2) {  // y0 = loMixed (14 valid; ghosts unused by valid pairs)
    h8 v = *reinterpret_cast<const h8*>(ws + (size_t)NROWS * 1160 + (size_t)row * 16 + 8 * lane);
#pragma unroll
    for (int i = 0; i < 8; ++i) ping[8 * lane + i] = (float)v[i];
  }

  float* cur = ping;
  float* dst = pong;
#pragma unroll
  for (int s = 0; s < 8; ++s) {
    const int N = LENSY[s];
    const int NP = N - 5;            // output pairs
    const int PCH = (NP + 7) / 8;    // 2,2,3,5,9,17,33,64 -> always <= 64
    const half_t* hsrc = ws + (size_t)NROWS * HSOFF[s] + (size_t)row * HSSTR[s];
    const int q = lane;
    if (q < PCH) {
      const int m0 = 8 * q;
      float lv[16];
#pragma unroll
      for (int r = 0; r < 4; ++r) {
        float4 a = *reinterpret_cast<const float4*>(cur + m0 + 4 * r);
        lv[4 * r] = a.x; lv[4 * r + 1] = a.y; lv[4 * r + 2] = a.z; lv[4 * r + 3] = a.w;
      }
      float hv[16];
      {
        h8 hA = *reinterpret_cast<const h8*>(hsrc + m0);
        h8 hB = *reinterpret_cast<const h8*>(hsrc + m0 + 8);
#pragma unroll
        for (int i = 0; i < 8; ++i) { hv[i] = (float)hA[i]; hv[8 + i] = (float)hB[i]; }
      }
      f2 a[8];
#pragma unroll
      for (int d = 0; d < 8; ++d) a[d] = (f2){0.f, 0.f};
#pragma unroll
      for (int t = 0; t < 6; ++t) {
        f2 dl = (f2){DEC_LO[2 * t + 1], DEC_LO[2 * t]};
        f2 dh = (f2){DEC_HI[2 * t + 1], DEC_HI[2 * t]};
#pragma unroll
        for (int d = 0; d < 8; ++d) a[d] += lv[d + t] * dl + hv[d + t] * dh;
      }
      if (s == 7) {  // NP=512: all chunks full; coalesced float4 stores
        float* orow = out + (size_t)row * 1024 + 2 * m0;
#pragma unroll
        for (int d = 0; d < 4; ++d)
          *reinterpret_cast<float4*>(orow + 4 * d) =
              make_float4(a[2 * d].x, a[2 * d].y, a[2 * d + 1].x, a[2 * d + 1].y);
      } else {
#pragma unroll
        for (int d = 0; d < 8; ++d)
          if (m0 + d < NP) *reinterpret_cast<f2*>(dst + 2 * (m0 + d)) = a[d];
      }
    }
    if (s < 7) { float* t = cur; cur = dst; dst = t; }
  }
}

// einsum('bix,iox->box') at len 14; in/out fp16 (stride 16), w fp32.
__global__ void mix_kernel(const half_t* __restrict__ in, const float* __restrict__ w,
                           half_t* __restrict__ out) {
  __shared__ float s_in[4][896];
  int b0 = blockIdx.x * 4;
  int t = threadIdx.x;  // 896 threads; t -> (i or o = t/14, x = t%14)
  int i = t / 14, xx = t % 14;
#pragma unroll
  for (int bb = 0; bb < 4; ++bb)
    s_in[bb][t] = (float)in[((size_t)(b0 + bb) * 64 + i) * 16 + xx];
  __syncthreads();
  float acc[4] = {0.f, 0.f, 0.f, 0.f};
#pragma unroll 8
  for (int k = 0; k < 64; ++k) {
    float wv = w[k * 896 + t];
#pragma unroll
    for (int bb = 0; bb < 4; ++bb) acc[bb] += s_in[bb][k * 14 + xx] * wv;
  }
#pragma unroll
  for (int bb = 0; bb < 4; ++bb)
    out[((size_t)(b0 + bb) * 64 + i) * 16 + xx] = (half_t)acc[bb];
}

extern "C" void kernel_launch(void* const* d_in, const int* in_sizes, int n_in,
                              void* d_out, int out_size, void* d_ws, size_t ws_size,
                              hipStream_t stream) {
  (void)in_sizes; (void)n_in; (void)out_size; (void)ws_size;
  const float* x  = (const float*)d_in[0];
  const float* w1 = (const float*)d_in[1];
  const float* w2 = (const float*)d_in[2];
  float* out = (float*)d_out;
  half_t* ws = (half_t*)d_ws;

  afb_fused<<<NROWS / WPB, 64 * WPB, 0, stream>>>(x, ws);

  half_t* loFinal = ws + (size_t)NROWS * 1128;
  half_t* hm      = ws + (size_t)NROWS * 1144;
  half_t* loMixed = ws + (size_t)NROWS * 1160;
  half_t* hi7     = ws + (size_t)NROWS * 1112;
  mix_kernel<<<64, 896, 0, stream>>>(loFinal, w1, loMixed);
  mix_kernel<<<64, 896, 0, stream>>>(hi7, w2, hm);

  sfb_fused<<<NROWS / WPB, 64 * WPB, 0, stream>>>(ws, out);
}

// Round 6
// 77.918 us; speedup vs baseline: 1.3298x; 1.3298x over previous
//
#include <hip/hip_runtime.h>

typedef float f2 __attribute__((ext_vector_type(2)));
typedef _Float16 half_t;
typedef _Float16 h4 __attribute__((ext_vector_type(4)));
typedef _Float16 h8 __attribute__((ext_vector_type(8)));

// Compile-time filter constants (fold to literals).
static constexpr float REC_LO[12] = {
  0.11154074335008017f, 0.4946238903983854f, 0.7511339080215775f, 0.3152503517092432f,
  -0.22626469396516913f, -0.12976686756709563f, 0.09750160558707936f, 0.02752286553001629f,
  -0.031582039318031156f, 0.0005538422009938016f, 0.004777257511010651f, -0.00107730108499558f };
static constexpr float REC_HI[12] = {
  -0.00107730108499558f, -0.004777257511010651f, 0.0005538422009938016f, 0.031582039318031156f,
  0.02752286553001629f, -0.09750160558707936f, -0.12976686756709563f, 0.22626469396516913f,
  0.3152503517092432f, -0.7511339080215775f, 0.4946238903983854f, -0.11154074335008017f };
static constexpr float DEC_LO[12] = {
  -0.00107730108499558f, 0.004777257511010651f, 0.0005538422009938016f, -0.031582039318031156f,
  0.02752286553001629f, 0.09750160558707936f, -0.12976686756709563f, -0.22626469396516913f,
  0.3152503517092432f, 0.7511339080215775f, 0.4946238903983854f, 0.11154074335008017f };
static constexpr float DEC_HI[12] = {
  -0.11154074335008017f, 0.4946238903983854f, -0.7511339080215775f, 0.3152503517092432f,
  0.22626469396516913f, -0.12976686756709563f, -0.09750160558707936f, 0.02752286553001629f,
  0.031582039318031156f, 0.0005538422009938016f, -0.004777257511010651f, -0.00107730108499558f };

#define NROWS 16384
#define WPB 4  // waves (= rows) per block

// ws layout in HALF elements, per-row strides padded to x8 for 16B alignment:
//  hi0 520@0, hi1 264@520, hi2 144@784, hi3 80@928, hi4 48@1008, hi5 32@1056,
//  hi6 24@1088, hi7 16@1112, loFinal 16@1128, hm 16@1144, loMixed 16@1160.
//  Total 1176 halves/row = 38.5 MB.

// ---------------- Fused 8-level analysis: one WAVE per row ----------------
// (unchanged from previous round — measured ~34 us)
__global__ __launch_bounds__(256) void afb_fused(const float* __restrict__ x,
                                                 half_t* __restrict__ ws) {
  __shared__ float sA[WPB][548];  // origin 14: lo1 (517) + pads
  __shared__ float sB[WPB][296];  // origin 14: lo2 (264) + pads
  constexpr int LENS[9] = {1024, 517, 264, 137, 74, 42, 26, 18, 14};
  constexpr int HSTR[8] = {520, 264, 144, 80, 48, 32, 24, 16};
  constexpr int HOFF[8] = {0, 520, 784, 928, 1008, 1056, 1088, 1112};
  const int wid = threadIdx.x >> 6;
  const int lane = threadIdx.x & 63;
  const int row = blockIdx.x * WPB + wid;
  float* bufA = sA[wid];
  float* bufB = sB[wid];

  const float* xrow = x + (size_t)row * 1024;
  half_t* hi0 = ws + (size_t)row * 520;

  // ---- Level 0: 65 chunks of 8 outputs (chunk 64 has 5 valid) ----
#pragma unroll
  for (int it = 0; it < 2; ++it) {
    int q = it * 64 + lane;
    if (q < 65) {
      int base = (q == 0) ? 0 : ((q == 64) ? 996 : 16 * q - 12);
      float xv[28];
#pragma unroll
      for (int r = 0; r < 7; ++r) {
        float4 v = *reinterpret_cast<const float4*>(xrow + base + 4 * r);
        xv[4 * r] = v.x; xv[4 * r + 1] = v.y; xv[4 * r + 2] = v.z; xv[4 * r + 3] = v.w;
      }
      // window w[e] = x_sym[16q - 10 + e], e in [0,26)
      float w[26];
      if (q == 0) {
#pragma unroll
        for (int e = 0; e < 26; ++e) w[e] = xv[e < 10 ? 9 - e : e - 10];
      } else if (q == 64) {
#pragma unroll
        for (int e = 0; e < 26; ++e) w[e] = (e < 10) ? xv[18 + e] : ((e < 20) ? xv[37 - e] : 0.f);
      } else {
#pragma unroll
        for (int e = 0; e < 26; ++e) w[e] = xv[2 + e];
      }
      f2 a[8];
#pragma unroll
      for (int d = 0; d < 8; ++d) a[d] = (f2){0.f, 0.f};
#pragma unroll
      for (int k = 0; k < 12; ++k) {
        f2 c = (f2){REC_LO[k], REC_HI[k]};
#pragma unroll
        for (int d = 0; d < 8; ++d) a[d] += w[2 * d + k] * c;
      }
      if (q < 64) {
#pragma unroll
        for (int d = 0; d < 4; ++d)
          *reinterpret_cast<f2*>(bufA + 14 + 8 * q + 2 * d) = (f2){a[2 * d].x, a[2 * d + 1].x};
        h8 hh;
#pragma unroll
        for (int d = 0; d < 8; ++d) hh[d] = (half_t)a[d].y;
        *reinterpret_cast<h8*>(hi0 + 8 * q) = hh;
      } else {  // outputs 512..516
#pragma unroll
        for (int d = 0; d < 5; ++d) {
          bufA[14 + 512 + d] = a[d].x;
          hi0[512 + d] = (half_t)a[d].y;
        }
      }
    }
  }
  // symmetric pads for level 1 (same-wave LDS ordering)
  if (lane < 10) bufA[13 - lane] = bufA[14 + lane];
  if (lane < 11) bufA[14 + 517 + lane] = bufA[14 + 516 - lane];

  float* cur = bufA;
  float* dst = bufB;
#pragma unroll
  for (int j = 1; j < 8; ++j) {
    const int outN = LENS[j + 1];
    const int NCH = (outN + 3) / 4;
    half_t* hiRow = ws + (size_t)NROWS * HOFF[j] + (size_t)row * HSTR[j];
#pragma unroll
    for (int q0 = 0; q0 < NCH; q0 += 64) {
      int q = q0 + lane;
      if (q < NCH) {
        const float* pp = cur + 8 * q + 4;  // padded idx of tap 0 for n0 = 4q
        float xv[20];
#pragma unroll
        for (int r = 0; r < 5; ++r) {
          float4 v = *reinterpret_cast<const float4*>(pp + 4 * r);
          xv[4 * r] = v.x; xv[4 * r + 1] = v.y; xv[4 * r + 2] = v.z; xv[4 * r + 3] = v.w;
        }
        f2 a0 = {0.f, 0.f}, a1 = {0.f, 0.f}, a2 = {0.f, 0.f}, a3 = {0.f, 0.f};
#pragma unroll
        for (int k = 0; k < 12; ++k) {
          f2 c = (f2){REC_LO[k], REC_HI[k]};
          a0 += xv[k] * c; a1 += xv[2 + k] * c; a2 += xv[4 + k] * c; a3 += xv[6 + k] * c;
        }
        if (j < 7) {
          *reinterpret_cast<f2*>(dst + 14 + 4 * q) = (f2){a0.x, a1.x};
          *reinterpret_cast<f2*>(dst + 16 + 4 * q) = (f2){a2.x, a3.x};
        } else {  // final lo (14) -> fp16
          h4 hl; hl[0] = (half_t)a0.x; hl[1] = (half_t)a1.x; hl[2] = (half_t)a2.x; hl[3] = (half_t)a3.x;
          *reinterpret_cast<h4*>(ws + (size_t)NROWS * 1128 + (size_t)row * 16 + 4 * q) = hl;
        }
        h4 hh; hh[0] = (half_t)a0.y; hh[1] = (half_t)a1.y; hh[2] = (half_t)a2.y; hh[3] = (half_t)a3.y;
        *reinterpret_cast<h4*>(hiRow + 4 * q) = hh;
      }
    }
    if (j < 7) {
      if (lane < 10) dst[13 - lane] = dst[14 + lane];
      if (lane < 11) dst[14 + outN + lane] = dst[14 + outN - 1 - lane];
      float* t = cur; cur = dst; dst = t;
    }
  }
}

// ---------------- Fused 8-level synthesis: one WAVE per row ----------------
// Round-3 proven access shapes: 4-wide chunks, DENSE 16B-lane-stride LDS reads
// (cur + 4q), unmasked paired float4 writes (ghosts land in slack, only ever
// feed ghost pairs). hi comes straight from global fp16 (VMEM pipe) — no LDS
// staging. Per-row LDS wave-ops ~45 (was ~91).
__global__ __launch_bounds__(256) void sfb_fused(const half_t* __restrict__ ws,
                                                 float* __restrict__ out) {
  __shared__ float sP[WPB][280];  // y0,y2,y4,y6 (max needed idx 267)
  __shared__ float sQ[WPB][544];  // y1,y3,y5,y7 (max written idx 527)
  constexpr int LENSY[8] = {14, 18, 26, 42, 74, 137, 264, 517};
  constexpr int HSOFF[8] = {1144, 1088, 1056, 1008, 928, 784, 520, 0};  // hm, hi6..hi0
  constexpr int HSSTR[8] = {16, 24, 32, 48, 80, 144, 264, 520};
  const int wid = threadIdx.x >> 6;
  const int lane = threadIdx.x & 63;
  const int row = blockIdx.x * WPB + wid;
  float* ping = sP[wid];
  float* pong = sQ[wid];

  if (lane < 2) {  // y0 = loMixed (14 valid; 14,15 ghost-only)
    h8 v = *reinterpret_cast<const h8*>(ws + (size_t)NROWS * 1160 + (size_t)row * 16 + 8 * lane);
    *reinterpret_cast<float4*>(ping + 8 * lane) =
        make_float4((float)v[0], (float)v[1], (float)v[2], (float)v[3]);
    *reinterpret_cast<float4*>(ping + 8 * lane + 4) =
        make_float4((float)v[4], (float)v[5], (float)v[6], (float)v[7]);
  }

  float* cur = ping;
  float* dst = pong;
#pragma unroll
  for (int s = 0; s < 8; ++s) {
    const int N = LENSY[s];
    const int NP = N - 5;            // output pairs
    const int PCH = (NP + 3) / 4;    // 3,4,6,10,18,33,65,128
    const half_t* hsrc = ws + (size_t)NROWS * HSOFF[s] + (size_t)row * HSSTR[s];
#pragma unroll
    for (int q0 = 0; q0 < PCH; q0 += 64) {
      int q = q0 + lane;
      if (q < PCH) {
        const int m0 = 4 * q;
        // lo: dense LDS reads (lane stride 16B) + one scalar for index 8
        float lv[9];
        {
          float4 a = *reinterpret_cast<const float4*>(cur + m0);
          float4 b = *reinterpret_cast<const float4*>(cur + m0 + 4);
          lv[0] = a.x; lv[1] = a.y; lv[2] = a.z; lv[3] = a.w;
          lv[4] = b.x; lv[5] = b.y; lv[6] = b.z; lv[7] = b.w;
          lv[8] = cur[m0 + 8];
        }
        // hi: straight from global fp16 (2x dwordx2 + 1 scalar)
        float hv[9];
        {
          h4 h0 = *reinterpret_cast<const h4*>(hsrc + m0);
          h4 h1 = *reinterpret_cast<const h4*>(hsrc + m0 + 4);
          half_t h2 = hsrc[m0 + 8];
          hv[0] = (float)h0[0]; hv[1] = (float)h0[1]; hv[2] = (float)h0[2]; hv[3] = (float)h0[3];
          hv[4] = (float)h1[0]; hv[5] = (float)h1[1]; hv[6] = (float)h1[2]; hv[7] = (float)h1[3];
          hv[8] = (float)h2;
        }
        f2 a0 = {0.f, 0.f}, a1 = {0.f, 0.f}, a2 = {0.f, 0.f}, a3 = {0.f, 0.f};
#pragma unroll
        for (int t = 0; t < 6; ++t) {
          f2 dl = (f2){DEC_LO[2 * t + 1], DEC_LO[2 * t]};
          f2 dh = (f2){DEC_HI[2 * t + 1], DEC_HI[2 * t]};
          a0 += lv[t] * dl + hv[t] * dh;
          a1 += lv[1 + t] * dl + hv[1 + t] * dh;
          a2 += lv[2 + t] * dl + hv[2 + t] * dh;
          a3 += lv[3 + t] * dl + hv[3 + t] * dh;
        }
        if (s < 7) {  // unmasked paired stores (round-3 proven shape)
          *reinterpret_cast<float4*>(dst + 2 * m0)     = make_float4(a0.x, a0.y, a1.x, a1.y);
          *reinterpret_cast<float4*>(dst + 2 * m0 + 4) = make_float4(a2.x, a2.y, a3.x, a3.y);
        } else {      // NP=512 exact: coalesced float4 stores
          float* orow = out + (size_t)row * 1024 + 2 * m0;
          *reinterpret_cast<float4*>(orow)     = make_float4(a0.x, a0.y, a1.x, a1.y);
          *reinterpret_cast<float4*>(orow + 4) = make_float4(a2.x, a2.y, a3.x, a3.y);
        }
      }
    }
    if (s < 7) { float* t = cur; cur = dst; dst = t; }
  }
}

// einsum('bix,iox->box') at len 14; in/out fp16 (stride 16), w fp32.
__global__ void mix_kernel(const half_t* __restrict__ in, const float* __restrict__ w,
                           half_t* __restrict__ out) {
  __shared__ float s_in[4][896];
  int b0 = blockIdx.x * 4;
  int t = threadIdx.x;  // 896 threads; t -> (i or o = t/14, x = t%14)
  int i = t / 14, xx = t % 14;
#pragma unroll
  for (int bb = 0; bb < 4; ++bb)
    s_in[bb][t] = (float)in[((size_t)(b0 + bb) * 64 + i) * 16 + xx];
  __syncthreads();
  float acc[4] = {0.f, 0.f, 0.f, 0.f};
#pragma unroll 8
  for (int k = 0; k < 64; ++k) {
    float wv = w[k * 896 + t];
#pragma unroll
    for (int bb = 0; bb < 4; ++bb) acc[bb] += s_in[bb][k * 14 + xx] * wv;
  }
#pragma unroll
  for (int bb = 0; bb < 4; ++bb)
    out[((size_t)(b0 + bb) * 64 + i) * 16 + xx] = (half_t)acc[bb];
}

extern "C" void kernel_launch(void* const* d_in, const int* in_sizes, int n_in,
                              void* d_out, int out_size, void* d_ws, size_t ws_size,
                              hipStream_t stream) {
  (void)in_sizes; (void)n_in; (void)out_size; (void)ws_size;
  const float* x  = (const float*)d_in[0];
  const float* w1 = (const float*)d_in[1];
  const float* w2 = (const float*)d_in[2];
  float* out = (float*)d_out;
  half_t* ws = (half_t*)d_ws;

  afb_fused<<<NROWS / WPB, 64 * WPB, 0, stream>>>(x, ws);

  half_t* loFinal = ws + (size_t)NROWS * 1128;
  half_t* hm      = ws + (size_t)NROWS * 1144;
  half_t* loMixed = ws + (size_t)NROWS * 1160;
  half_t* hi7     = ws + (size_t)NROWS * 1112;
  mix_kernel<<<64, 896, 0, stream>>>(loFinal, w1, loMixed);
  mix_kernel<<<64, 896, 0, stream>>>(hi7, w2, hm);

  sfb_fused<<<NROWS / WPB, 64 * WPB, 0, stream>>>(ws, out);
}

// Round 7
// 71.563 us; speedup vs baseline: 1.4479x; 1.0888x over previous
//
#include <hip/hip_runtime.h>

typedef float f2 __attribute__((ext_vector_type(2)));
typedef _Float16 half_t;
typedef _Float16 h4 __attribute__((ext_vector_type(4)));
typedef _Float16 h8 __attribute__((ext_vector_type(8)));

// Compile-time filter constants (fold to literals).
static constexpr float REC_LO[12] = {
  0.11154074335008017f, 0.4946238903983854f, 0.7511339080215775f, 0.3152503517092432f,
  -0.22626469396516913f, -0.12976686756709563f, 0.09750160558707936f, 0.02752286553001629f,
  -0.031582039318031156f, 0.0005538422009938016f, 0.004777257511010651f, -0.00107730108499558f };
static constexpr float REC_HI[12] = {
  -0.00107730108499558f, -0.004777257511010651f, 0.0005538422009938016f, 0.031582039318031156f,
  0.02752286553001629f, -0.09750160558707936f, -0.12976686756709563f, 0.22626469396516913f,
  0.3152503517092432f, -0.7511339080215775f, 0.4946238903983854f, -0.11154074335008017f };
static constexpr float DEC_LO[12] = {
  -0.00107730108499558f, 0.004777257511010651f, 0.0005538422009938016f, -0.031582039318031156f,
  0.02752286553001629f, 0.09750160558707936f, -0.12976686756709563f, -0.22626469396516913f,
  0.3152503517092432f, 0.7511339080215775f, 0.4946238903983854f, 0.11154074335008017f };
static constexpr float DEC_HI[12] = {
  -0.11154074335008017f, 0.4946238903983854f, -0.7511339080215775f, 0.3152503517092432f,
  0.22626469396516913f, -0.12976686756709563f, -0.09750160558707936f, 0.02752286553001629f,
  0.031582039318031156f, 0.0005538422009938016f, -0.004777257511010651f, -0.00107730108499558f };

#define NROWS 16384
#define WPB 4  // waves (= rows) per block

// ws layout in HALF elements, per-row strides padded to x8 for 16B alignment:
//  hi0 520@0, hi1 264@520, hi2 144@784, hi3 80@928, hi4 48@1008, hi5 32@1056,
//  hi6 24@1088, hi7 16@1112, loFinal 16@1128, hm 16@1144, loMixed 16@1160.
//  Total 1176 halves/row = 38.5 MB.

// ---------------- Fused 8-level analysis: one WAVE per row ----------------
// L0: 64 chunks x 8 outputs, single iteration + 5-lane masked tail (512..516).
// L1: chunk-8, 33 lanes, single iteration.  L2-7: chunk-4, single iteration.
// Pads: left+right merged into one masked read + one write (21 lanes).
// All same-wave LDS dependencies (program order) — no barriers.
__global__ __launch_bounds__(256) void afb_fused(const float* __restrict__ x,
                                                 half_t* __restrict__ ws) {
  __shared__ float sA[WPB][548];  // origin 14: L0 out (517+tail+pads), L3/L5/L7 in
  __shared__ float sB[WPB][296];  // origin 14: L1 out (264+pads), L4/L6 in
  constexpr int LENS[9] = {1024, 517, 264, 137, 74, 42, 26, 18, 14};
  constexpr int HSTR[8] = {520, 264, 144, 80, 48, 32, 24, 16};
  constexpr int HOFF[8] = {0, 520, 784, 928, 1008, 1056, 1088, 1112};
  const int wid = threadIdx.x >> 6;
  const int lane = threadIdx.x & 63;
  const int row = blockIdx.x * WPB + wid;
  float* bufA = sA[wid];
  float* bufB = sB[wid];
  const float* xrow = x + (size_t)row * 1024;
  half_t* hi0 = ws + (size_t)row * 520;

  // ---- Level 0: outputs 0..511 in one full-wave pass ----
  {
    const int q = lane;
    const int base = (q == 0) ? 0 : 16 * q - 12;
    float xv[28];
#pragma unroll
    for (int r = 0; r < 7; ++r) {
      float4 v = *reinterpret_cast<const float4*>(xrow + base + 4 * r);
      xv[4 * r] = v.x; xv[4 * r + 1] = v.y; xv[4 * r + 2] = v.z; xv[4 * r + 3] = v.w;
    }
    // window w[e] = x_sym[16q - 10 + e], e in [0,26)
    float w[26];
    if (q == 0) {
#pragma unroll
      for (int e = 0; e < 26; ++e) w[e] = xv[e < 10 ? 9 - e : e - 10];
    } else {
#pragma unroll
      for (int e = 0; e < 26; ++e) w[e] = xv[2 + e];  // interior: max idx 1023, no reflect
    }
    f2 a[8];
#pragma unroll
    for (int d = 0; d < 8; ++d) a[d] = (f2){0.f, 0.f};
#pragma unroll
    for (int k = 0; k < 12; ++k) {
      f2 c = (f2){REC_LO[k], REC_HI[k]};
#pragma unroll
      for (int d = 0; d < 8; ++d) a[d] += w[2 * d + k] * c;
    }
#pragma unroll
    for (int d = 0; d < 4; ++d)
      *reinterpret_cast<f2*>(bufA + 14 + 8 * q + 2 * d) = (f2){a[2 * d].x, a[2 * d + 1].x};
    h8 hh;
#pragma unroll
    for (int d = 0; d < 8; ++d) hh[d] = (half_t)a[d].y;
    *reinterpret_cast<h8*>(hi0 + 8 * q) = hh;
  }
  // ---- Level 0 tail: outputs 512..516 on lanes 0..4 ----
  if (lane < 5) {
    const int i0 = 1014 + 2 * lane;  // first tap index (pre-reflection)
    float acL = 0.f, acH = 0.f;
#pragma unroll
    for (int k = 0; k < 12; ++k) {
      int idx = i0 + k;
      idx = min(idx, 2047 - idx);  // right symmetric reflection
      float v = xrow[idx];
      acL += v * REC_LO[k];
      acH += v * REC_HI[k];
    }
    bufA[14 + 512 + lane] = acL;
    hi0[512 + lane] = (half_t)acH;
  }
  // pads for level-1 input (merged: lanes 0..9 left, 10..20 right)
  if (lane < 21) {
    int d, s;
    if (lane < 10) { d = 13 - lane; s = 14 + lane; }
    else { int k = lane - 10; d = 14 + 517 + k; s = 14 + 516 - k; }
    bufA[d] = bufA[s];
  }

  // ---- Level 1: chunk-8, 33 lanes, single iteration (264 = 33*8 exact) ----
  if (lane < 33) {
    const float* pp = bufA + 16 * lane + 4;  // byte 64q+16: 16B aligned
    float xv[28];
#pragma unroll
    for (int r = 0; r < 7; ++r) {
      float4 v = *reinterpret_cast<const float4*>(pp + 4 * r);
      xv[4 * r] = v.x; xv[4 * r + 1] = v.y; xv[4 * r + 2] = v.z; xv[4 * r + 3] = v.w;
    }
    f2 a[8];
#pragma unroll
    for (int d = 0; d < 8; ++d) a[d] = (f2){0.f, 0.f};
#pragma unroll
    for (int k = 0; k < 12; ++k) {
      f2 c = (f2){REC_LO[k], REC_HI[k]};
#pragma unroll
      for (int d = 0; d < 8; ++d) a[d] += xv[2 * d + k] * c;
    }
#pragma unroll
    for (int d = 0; d < 4; ++d)
      *reinterpret_cast<f2*>(bufB + 14 + 8 * lane + 2 * d) = (f2){a[2 * d].x, a[2 * d + 1].x};
    h8 hh;
#pragma unroll
    for (int d = 0; d < 8; ++d) hh[d] = (half_t)a[d].y;
    *reinterpret_cast<h8*>(ws + (size_t)NROWS * 520 + (size_t)row * 264 + 8 * lane) = hh;
  }
  if (lane < 21) {  // pads for level-2 input
    int d, s;
    if (lane < 10) { d = 13 - lane; s = 14 + lane; }
    else { int k = lane - 10; d = 14 + 264 + k; s = 14 + 263 - k; }
    bufB[d] = bufB[s];
  }

  // ---- Levels 2..7: chunk-4, single iteration each ----
  float* cur = bufB;
  float* dst = bufA;
#pragma unroll
  for (int j = 2; j < 8; ++j) {
    const int outN = LENS[j + 1];
    const int NCH = (outN + 3) / 4;
    half_t* hiRow = ws + (size_t)NROWS * HOFF[j] + (size_t)row * HSTR[j];
    if (lane < NCH) {
      const float* pp = cur + 8 * lane + 4;
      float xv[20];
#pragma unroll
      for (int r = 0; r < 5; ++r) {
        float4 v = *reinterpret_cast<const float4*>(pp + 4 * r);
        xv[4 * r] = v.x; xv[4 * r + 1] = v.y; xv[4 * r + 2] = v.z; xv[4 * r + 3] = v.w;
      }
      f2 a0 = {0.f, 0.f}, a1 = {0.f, 0.f}, a2 = {0.f, 0.f}, a3 = {0.f, 0.f};
#pragma unroll
      for (int k = 0; k < 12; ++k) {
        f2 c = (f2){REC_LO[k], REC_HI[k]};
        a0 += xv[k] * c; a1 += xv[2 + k] * c; a2 += xv[4 + k] * c; a3 += xv[6 + k] * c;
      }
      if (j < 7) {
        *reinterpret_cast<f2*>(dst + 14 + 4 * lane) = (f2){a0.x, a1.x};
        *reinterpret_cast<f2*>(dst + 16 + 4 * lane) = (f2){a2.x, a3.x};
      } else {  // final lo (14) -> fp16 (garbage at 14,15 lands in stride slack)
        h4 hl; hl[0] = (half_t)a0.x; hl[1] = (half_t)a1.x; hl[2] = (half_t)a2.x; hl[3] = (half_t)a3.x;
        *reinterpret_cast<h4*>(ws + (size_t)NROWS * 1128 + (size_t)row * 16 + 4 * lane) = hl;
      }
      h4 hh; hh[0] = (half_t)a0.y; hh[1] = (half_t)a1.y; hh[2] = (half_t)a2.y; hh[3] = (half_t)a3.y;
      *reinterpret_cast<h4*>(hiRow + 4 * lane) = hh;
    }
    if (j < 7) {
      if (lane < 21) {  // merged pads (also overwrite chunk-ghost values)
        int d, s;
        if (lane < 10) { d = 13 - lane; s = 14 + lane; }
        else { int k = lane - 10; d = 14 + outN + k; s = 14 + outN - 1 - k; }
        dst[d] = dst[s];
      }
      float* t = cur; cur = dst; dst = t;
    }
  }
}

// ---------------- Fused 8-level synthesis: one WAVE per row (unchanged) ----------------
__global__ __launch_bounds__(256) void sfb_fused(const half_t* __restrict__ ws,
                                                 float* __restrict__ out) {
  __shared__ float sP[WPB][280];  // y0,y2,y4,y6 (max needed idx 267)
  __shared__ float sQ[WPB][544];  // y1,y3,y5,y7 (max written idx 527)
  constexpr int LENSY[8] = {14, 18, 26, 42, 74, 137, 264, 517};
  constexpr int HSOFF[8] = {1144, 1088, 1056, 1008, 928, 784, 520, 0};  // hm, hi6..hi0
  constexpr int HSSTR[8] = {16, 24, 32, 48, 80, 144, 264, 520};
  const int wid = threadIdx.x >> 6;
  const int lane = threadIdx.x & 63;
  const int row = blockIdx.x * WPB + wid;
  float* ping = sP[wid];
  float* pong = sQ[wid];

  if (lane < 2) {  // y0 = loMixed (14 valid; 14,15 ghost-only)
    h8 v = *reinterpret_cast<const h8*>(ws + (size_t)NROWS * 1160 + (size_t)row * 16 + 8 * lane);
    *reinterpret_cast<float4*>(ping + 8 * lane) =
        make_float4((float)v[0], (float)v[1], (float)v[2], (float)v[3]);
    *reinterpret_cast<float4*>(ping + 8 * lane + 4) =
        make_float4((float)v[4], (float)v[5], (float)v[6], (float)v[7]);
  }

  float* cur = ping;
  float* dst = pong;
#pragma unroll
  for (int s = 0; s < 8; ++s) {
    const int N = LENSY[s];
    const int NP = N - 5;            // output pairs
    const int PCH = (NP + 3) / 4;    // 3,4,6,10,18,33,65,128
    const half_t* hsrc = ws + (size_t)NROWS * HSOFF[s] + (size_t)row * HSSTR[s];
#pragma unroll
    for (int q0 = 0; q0 < PCH; q0 += 64) {
      int q = q0 + lane;
      if (q < PCH) {
        const int m0 = 4 * q;
        float lv[9];
        {
          float4 a = *reinterpret_cast<const float4*>(cur + m0);
          float4 b = *reinterpret_cast<const float4*>(cur + m0 + 4);
          lv[0] = a.x; lv[1] = a.y; lv[2] = a.z; lv[3] = a.w;
          lv[4] = b.x; lv[5] = b.y; lv[6] = b.z; lv[7] = b.w;
          lv[8] = cur[m0 + 8];
        }
        float hv[9];
        {
          h4 h0 = *reinterpret_cast<const h4*>(hsrc + m0);
          h4 h1 = *reinterpret_cast<const h4*>(hsrc + m0 + 4);
          half_t h2 = hsrc[m0 + 8];
          hv[0] = (float)h0[0]; hv[1] = (float)h0[1]; hv[2] = (float)h0[2]; hv[3] = (float)h0[3];
          hv[4] = (float)h1[0]; hv[5] = (float)h1[1]; hv[6] = (float)h1[2]; hv[7] = (float)h1[3];
          hv[8] = (float)h2;
        }
        f2 a0 = {0.f, 0.f}, a1 = {0.f, 0.f}, a2 = {0.f, 0.f}, a3 = {0.f, 0.f};
#pragma unroll
        for (int t = 0; t < 6; ++t) {
          f2 dl = (f2){DEC_LO[2 * t + 1], DEC_LO[2 * t]};
          f2 dh = (f2){DEC_HI[2 * t + 1], DEC_HI[2 * t]};
          a0 += lv[t] * dl + hv[t] * dh;
          a1 += lv[1 + t] * dl + hv[1 + t] * dh;
          a2 += lv[2 + t] * dl + hv[2 + t] * dh;
          a3 += lv[3 + t] * dl + hv[3 + t] * dh;
        }
        if (s < 7) {
          *reinterpret_cast<float4*>(dst + 2 * m0)     = make_float4(a0.x, a0.y, a1.x, a1.y);
          *reinterpret_cast<float4*>(dst + 2 * m0 + 4) = make_float4(a2.x, a2.y, a3.x, a3.y);
        } else {      // NP=512 exact: coalesced float4 stores
          float* orow = out + (size_t)row * 1024 + 2 * m0;
          *reinterpret_cast<float4*>(orow)     = make_float4(a0.x, a0.y, a1.x, a1.y);
          *reinterpret_cast<float4*>(orow + 4) = make_float4(a2.x, a2.y, a3.x, a3.y);
        }
      }
    }
    if (s < 7) { float* t = cur; cur = dst; dst = t; }
  }
}

// Both einsums in ONE launch: blocks 0..63 -> lo mix (w1), 64..127 -> hi mix (w2).
__global__ void mix_both(half_t* __restrict__ ws, const float* __restrict__ w1,
                         const float* __restrict__ w2) {
  __shared__ float s_in[4][896];
  const int which = blockIdx.x >> 6;  // 0: loFinal->loMixed, 1: hi7->hm
  const half_t* in = ws + (size_t)NROWS * (which ? 1112 : 1128);
  const float* w = which ? w2 : w1;
  half_t* out = ws + (size_t)NROWS * (which ? 1144 : 1160);
  int b0 = (blockIdx.x & 63) * 4;
  int t = threadIdx.x;  // 896 threads; t -> (i or o = t/14, x = t%14)
  int i = t / 14, xx = t % 14;
#pragma unroll
  for (int bb = 0; bb < 4; ++bb)
    s_in[bb][t] = (float)in[((size_t)(b0 + bb) * 64 + i) * 16 + xx];
  __syncthreads();
  float acc[4] = {0.f, 0.f, 0.f, 0.f};
#pragma unroll 8
  for (int k = 0; k < 64; ++k) {
    float wv = w[k * 896 + t];
#pragma unroll
    for (int bb = 0; bb < 4; ++bb) acc[bb] += s_in[bb][k * 14 + xx] * wv;
  }
#pragma unroll
  for (int bb = 0; bb < 4; ++bb)
    out[((size_t)(b0 + bb) * 64 + i) * 16 + xx] = (half_t)acc[bb];
}

extern "C" void kernel_launch(void* const* d_in, const int* in_sizes, int n_in,
                              void* d_out, int out_size, void* d_ws, size_t ws_size,
                              hipStream_t stream) {
  (void)in_sizes; (void)n_in; (void)out_size; (void)ws_size;
  const float* x  = (const float*)d_in[0];
  const float* w1 = (const float*)d_in[1];
  const float* w2 = (const float*)d_in[2];
  float* out = (float*)d_out;
  half_t* ws = (half_t*)d_ws;

  afb_fused<<<NROWS / WPB, 64 * WPB, 0, stream>>>(x, ws);
  mix_both<<<128, 896, 0, stream>>>(ws, w1, w2);
  sfb_fused<<<NROWS / WPB, 64 * WPB, 0, stream>>>(ws, out);
}

// Round 8
// 63.279 us; speedup vs baseline: 1.6374x; 1.1309x over previous
//
#include <hip/hip_runtime.h>

typedef float f2 __attribute__((ext_vector_type(2)));
typedef _Float16 half_t;
typedef _Float16 h4 __attribute__((ext_vector_type(4)));
typedef _Float16 h8 __attribute__((ext_vector_type(8)));

// Compile-time filter constants (fold to literals).
static constexpr float REC_LO[12] = {
  0.11154074335008017f, 0.4946238903983854f, 0.7511339080215775f, 0.3152503517092432f,
  -0.22626469396516913f, -0.12976686756709563f, 0.09750160558707936f, 0.02752286553001629f,
  -0.031582039318031156f, 0.0005538422009938016f, 0.004777257511010651f, -0.00107730108499558f };
static constexpr float REC_HI[12] = {
  -0.00107730108499558f, -0.004777257511010651f, 0.0005538422009938016f, 0.031582039318031156f,
  0.02752286553001629f, -0.09750160558707936f, -0.12976686756709563f, 0.22626469396516913f,
  0.3152503517092432f, -0.7511339080215775f, 0.4946238903983854f, -0.11154074335008017f };
static constexpr float DEC_LO[12] = {
  -0.00107730108499558f, 0.004777257511010651f, 0.0005538422009938016f, -0.031582039318031156f,
  0.02752286553001629f, 0.09750160558707936f, -0.12976686756709563f, -0.22626469396516913f,
  0.3152503517092432f, 0.7511339080215775f, 0.4946238903983854f, 0.11154074335008017f };
static constexpr float DEC_HI[12] = {
  -0.11154074335008017f, 0.4946238903983854f, -0.7511339080215775f, 0.3152503517092432f,
  0.22626469396516913f, -0.12976686756709563f, -0.09750160558707936f, 0.02752286553001629f,
  0.031582039318031156f, 0.0005538422009938016f, -0.004777257511010651f, -0.00107730108499558f };

#define NROWS 16384
#define WPB 4  // waves (= rows) per block

// ws layout in HALF elements, per-row strides padded to x8 for 16B alignment:
//  hi0 520@0, hi1 264@520, hi2 144@784, hi3 80@928, hi4 48@1008, hi5 32@1056,
//  hi6 24@1088, hi7 16@1112, loFinal 16@1128, hm 16@1144, loMixed 16@1160.

// ---------------- Fused 8-level analysis ----------------
// Phase 1 (all 4 waves, own row): L0 direct-from-global + tail + pads, L1 + pads.
// Phase 2 (wave 0 only, after barrier): levels 2..7 for ALL 4 rows packed as
// 16-lane groups (sub=lane>>4). Waves 1-3 exit. ~3x fewer wave-instrs deep.
__global__ __launch_bounds__(256) void afb_fused(const float* __restrict__ x,
                                                 half_t* __restrict__ ws) {
  __shared__ float sA[WPB][548];
  __shared__ float sB[WPB][296];
  constexpr int LENS[9] = {1024, 517, 264, 137, 74, 42, 26, 18, 14};
  constexpr int HSTR[8] = {520, 264, 144, 80, 48, 32, 24, 16};
  constexpr int HOFF[8] = {0, 520, 784, 928, 1008, 1056, 1088, 1112};
  const int wid = threadIdx.x >> 6;
  const int lane = threadIdx.x & 63;
  const int row = blockIdx.x * WPB + wid;
  float* bufA = sA[wid];
  float* bufB = sB[wid];
  const float* xrow = x + (size_t)row * 1024;
  half_t* hi0 = ws + (size_t)row * 520;

  // ---- Level 0: outputs 0..511, one full-wave pass ----
  {
    const int q = lane;
    const int base = (q == 0) ? 0 : 16 * q - 12;
    float xv[28];
#pragma unroll
    for (int r = 0; r < 7; ++r) {
      float4 v = *reinterpret_cast<const float4*>(xrow + base + 4 * r);
      xv[4 * r] = v.x; xv[4 * r + 1] = v.y; xv[4 * r + 2] = v.z; xv[4 * r + 3] = v.w;
    }
    float w[26];
    if (q == 0) {
#pragma unroll
      for (int e = 0; e < 26; ++e) w[e] = xv[e < 10 ? 9 - e : e - 10];
    } else {
#pragma unroll
      for (int e = 0; e < 26; ++e) w[e] = xv[2 + e];
    }
    f2 a[8];
#pragma unroll
    for (int d = 0; d < 8; ++d) a[d] = (f2){0.f, 0.f};
#pragma unroll
    for (int k = 0; k < 12; ++k) {
      f2 c = (f2){REC_LO[k], REC_HI[k]};
#pragma unroll
      for (int d = 0; d < 8; ++d) a[d] += w[2 * d + k] * c;
    }
#pragma unroll
    for (int d = 0; d < 4; ++d)
      *reinterpret_cast<f2*>(bufA + 14 + 8 * q + 2 * d) = (f2){a[2 * d].x, a[2 * d + 1].x};
    h8 hh;
#pragma unroll
    for (int d = 0; d < 8; ++d) hh[d] = (half_t)a[d].y;
    *reinterpret_cast<h8*>(hi0 + 8 * q) = hh;
  }
  // ---- Level 0 tail: outputs 512..516 on lanes 0..4 ----
  if (lane < 5) {
    const int i0 = 1014 + 2 * lane;
    float acL = 0.f, acH = 0.f;
#pragma unroll
    for (int k = 0; k < 12; ++k) {
      int idx = i0 + k;
      idx = min(idx, 2047 - idx);
      float v = xrow[idx];
      acL += v * REC_LO[k];
      acH += v * REC_HI[k];
    }
    bufA[14 + 512 + lane] = acL;
    hi0[512 + lane] = (half_t)acH;
  }
  if (lane < 21) {  // pads for level-1 input
    int d, s;
    if (lane < 10) { d = 13 - lane; s = 14 + lane; }
    else { int k = lane - 10; d = 14 + 517 + k; s = 14 + 516 - k; }
    bufA[d] = bufA[s];
  }

  // ---- Level 1: chunk-8, 33 lanes (264 = 33*8 exact) ----
  if (lane < 33) {
    const float* pp = bufA + 16 * lane + 4;
    float xv[28];
#pragma unroll
    for (int r = 0; r < 7; ++r) {
      float4 v = *reinterpret_cast<const float4*>(pp + 4 * r);
      xv[4 * r] = v.x; xv[4 * r + 1] = v.y; xv[4 * r + 2] = v.z; xv[4 * r + 3] = v.w;
    }
    f2 a[8];
#pragma unroll
    for (int d = 0; d < 8; ++d) a[d] = (f2){0.f, 0.f};
#pragma unroll
    for (int k = 0; k < 12; ++k) {
      f2 c = (f2){REC_LO[k], REC_HI[k]};
#pragma unroll
      for (int d = 0; d < 8; ++d) a[d] += xv[2 * d + k] * c;
    }
#pragma unroll
    for (int d = 0; d < 4; ++d)
      *reinterpret_cast<f2*>(bufB + 14 + 8 * lane + 2 * d) = (f2){a[2 * d].x, a[2 * d + 1].x};
    h8 hh;
#pragma unroll
    for (int d = 0; d < 8; ++d) hh[d] = (half_t)a[d].y;
    *reinterpret_cast<h8*>(ws + (size_t)NROWS * 520 + (size_t)row * 264 + 8 * lane) = hh;
  }
  if (lane < 21) {  // pads for level-2 input
    int d, s;
    if (lane < 10) { d = 13 - lane; s = 14 + lane; }
    else { int k = lane - 10; d = 14 + 264 + k; s = 14 + 263 - k; }
    bufB[d] = bufB[s];
  }

  __syncthreads();
  if (wid != 0) return;  // waves 1-3 done (no further barriers)

  // ---- Phase 2 (wave 0): levels 2..7 for 4 rows, 16-lane groups ----
  const int sub = lane >> 4, l16 = lane & 15;
  const int prow = blockIdx.x * WPB + sub;
  float* cur = sB[sub];
  float* dst = sA[sub];
  constexpr int NITS[8] = {0, 0, 3, 2, 1, 1, 1, 1};  // ceil(NCH/16)
#pragma unroll
  for (int j = 2; j < 8; ++j) {
    const int outN = LENS[j + 1];
    const int NCH = (outN + 3) / 4;
    half_t* hiRow = ws + (size_t)NROWS * HOFF[j] + (size_t)prow * HSTR[j];
#pragma unroll
    for (int it = 0; it < NITS[j]; ++it) {
      const int q = it * 16 + l16;
      if (q < NCH) {
        const float* pp = cur + 8 * q + 4;
        float xv[20];
#pragma unroll
        for (int r = 0; r < 5; ++r) {
          float4 v = *reinterpret_cast<const float4*>(pp + 4 * r);
          xv[4 * r] = v.x; xv[4 * r + 1] = v.y; xv[4 * r + 2] = v.z; xv[4 * r + 3] = v.w;
        }
        f2 a0 = {0.f, 0.f}, a1 = {0.f, 0.f}, a2 = {0.f, 0.f}, a3 = {0.f, 0.f};
#pragma unroll
        for (int k = 0; k < 12; ++k) {
          f2 c = (f2){REC_LO[k], REC_HI[k]};
          a0 += xv[k] * c; a1 += xv[2 + k] * c; a2 += xv[4 + k] * c; a3 += xv[6 + k] * c;
        }
        if (j < 7) {
          *reinterpret_cast<f2*>(dst + 14 + 4 * q) = (f2){a0.x, a1.x};
          *reinterpret_cast<f2*>(dst + 16 + 4 * q) = (f2){a2.x, a3.x};
        } else {  // final lo (14) -> fp16 (ghosts land in stride slack)
          h4 hl; hl[0] = (half_t)a0.x; hl[1] = (half_t)a1.x; hl[2] = (half_t)a2.x; hl[3] = (half_t)a3.x;
          *reinterpret_cast<h4*>(ws + (size_t)NROWS * 1128 + (size_t)prow * 16 + 4 * q) = hl;
        }
        h4 hh; hh[0] = (half_t)a0.y; hh[1] = (half_t)a1.y; hh[2] = (half_t)a2.y; hh[3] = (half_t)a3.y;
        *reinterpret_cast<h4*>(hiRow + 4 * q) = hh;
      }
    }
    if (j < 7) {
      if (l16 < 10) dst[13 - l16] = dst[14 + l16];         // left pads
      if (l16 < 11) dst[14 + outN + l16] = dst[14 + outN - 1 - l16];  // right pads (+ghost overwrite)
      float* t = cur; cur = dst; dst = t;
    }
  }
}

// ---------------- Fused 8-level synthesis ----------------
// Phase 1 (wave 0 only): s=0..5 for ALL 4 rows packed as 16-lane groups.
// Phase 2 (after barrier, all waves, own row): s=6 (65 chunks), s=7 (128 = 2x64
// exact, unmasked). hi always read directly from global fp16.
__global__ __launch_bounds__(256) void sfb_fused(const half_t* __restrict__ ws,
                                                 float* __restrict__ out) {
  __shared__ float sP[WPB][280];  // y0,y2,y4,y6 (max read idx 267)
  __shared__ float sQ[WPB][544];  // y1,y3,y5,y7 (max write idx 519)
  const int wid = threadIdx.x >> 6;
  const int lane = threadIdx.x & 63;

  if (wid == 0) {
    constexpr int LENSY[6] = {14, 18, 26, 42, 74, 137};
    constexpr int HSOFF[6] = {1144, 1088, 1056, 1008, 928, 784};  // hm, hi6..hi2
    constexpr int HSSTR[6] = {16, 24, 32, 48, 80, 144};
    constexpr int NITS[6] = {1, 1, 1, 1, 2, 3};  // ceil(PCH/16)
    const int sub = lane >> 4, l16 = lane & 15;
    const int prow = blockIdx.x * WPB + sub;
    float* cur = sP[sub];
    float* dst = sQ[sub];
    if (l16 < 2) {  // y0 = loMixed (14 valid; 14,15 ghost-only)
      h8 v = *reinterpret_cast<const h8*>(ws + (size_t)NROWS * 1160 + (size_t)prow * 16 + 8 * l16);
      *reinterpret_cast<float4*>(cur + 8 * l16) =
          make_float4((float)v[0], (float)v[1], (float)v[2], (float)v[3]);
      *reinterpret_cast<float4*>(cur + 8 * l16 + 4) =
          make_float4((float)v[4], (float)v[5], (float)v[6], (float)v[7]);
    }
#pragma unroll
    for (int s = 0; s < 6; ++s) {
      const int N = LENSY[s];
      const int NP = N - 5;
      const int PCH = (NP + 3) / 4;
      const half_t* hsrc = ws + (size_t)NROWS * HSOFF[s] + (size_t)prow * HSSTR[s];
#pragma unroll
      for (int it = 0; it < NITS[s]; ++it) {
        const int q = it * 16 + l16;
        if (q < PCH) {
          const int m0 = 4 * q;
          float lv[9];
          {
            float4 a = *reinterpret_cast<const float4*>(cur + m0);
            float4 b = *reinterpret_cast<const float4*>(cur + m0 + 4);
            lv[0] = a.x; lv[1] = a.y; lv[2] = a.z; lv[3] = a.w;
            lv[4] = b.x; lv[5] = b.y; lv[6] = b.z; lv[7] = b.w;
            lv[8] = cur[m0 + 8];
          }
          float hv[9];
          {
            h4 h0 = *reinterpret_cast<const h4*>(hsrc + m0);
            h4 h1 = *reinterpret_cast<const h4*>(hsrc + m0 + 4);
            half_t h2 = hsrc[m0 + 8];
            hv[0] = (float)h0[0]; hv[1] = (float)h0[1]; hv[2] = (float)h0[2]; hv[3] = (float)h0[3];
            hv[4] = (float)h1[0]; hv[5] = (float)h1[1]; hv[6] = (float)h1[2]; hv[7] = (float)h1[3];
            hv[8] = (float)h2;
          }
          f2 a0 = {0.f, 0.f}, a1 = {0.f, 0.f}, a2 = {0.f, 0.f}, a3 = {0.f, 0.f};
#pragma unroll
          for (int t = 0; t < 6; ++t) {
            f2 dl = (f2){DEC_LO[2 * t + 1], DEC_LO[2 * t]};
            f2 dh = (f2){DEC_HI[2 * t + 1], DEC_HI[2 * t]};
            a0 += lv[t] * dl + hv[t] * dh;
            a1 += lv[1 + t] * dl + hv[1 + t] * dh;
            a2 += lv[2 + t] * dl + hv[2 + t] * dh;
            a3 += lv[3 + t] * dl + hv[3 + t] * dh;
          }
          *reinterpret_cast<float4*>(dst + 2 * m0)     = make_float4(a0.x, a0.y, a1.x, a1.y);
          *reinterpret_cast<float4*>(dst + 2 * m0 + 4) = make_float4(a2.x, a2.y, a3.x, a3.y);
        }
      }
      float* t = cur; cur = dst; dst = t;
    }
    // after 6 swaps: y6 lives in sP[sub]
  }
  __syncthreads();

  // ---- Phase 2: all waves, own row ----
  const int row = blockIdx.x * WPB + wid;
  float* cur = sP[wid];
  float* dst = sQ[wid];
  // s = 6: N=264, NP=259, PCH=65
  {
    const half_t* hsrc = ws + (size_t)NROWS * 520 + (size_t)row * 264;  // hi1
#pragma unroll
    for (int q0 = 0; q0 < 65; q0 += 64) {
      const int q = q0 + lane;
      if (q < 65) {
        const int m0 = 4 * q;
        float lv[9];
        {
          float4 a = *reinterpret_cast<const float4*>(cur + m0);
          float4 b = *reinterpret_cast<const float4*>(cur + m0 + 4);
          lv[0] = a.x; lv[1] = a.y; lv[2] = a.z; lv[3] = a.w;
          lv[4] = b.x; lv[5] = b.y; lv[6] = b.z; lv[7] = b.w;
          lv[8] = cur[m0 + 8];
        }
        float hv[9];
        {
          h4 h0 = *reinterpret_cast<const h4*>(hsrc + m0);
          h4 h1 = *reinterpret_cast<const h4*>(hsrc + m0 + 4);
          half_t h2 = hsrc[m0 + 8];
          hv[0] = (float)h0[0]; hv[1] = (float)h0[1]; hv[2] = (float)h0[2]; hv[3] = (float)h0[3];
          hv[4] = (float)h1[0]; hv[5] = (float)h1[1]; hv[6] = (float)h1[2]; hv[7] = (float)h1[3];
          hv[8] = (float)h2;
        }
        f2 a0 = {0.f, 0.f}, a1 = {0.f, 0.f}, a2 = {0.f, 0.f}, a3 = {0.f, 0.f};
#pragma unroll
        for (int t = 0; t < 6; ++t) {
          f2 dl = (f2){DEC_LO[2 * t + 1], DEC_LO[2 * t]};
          f2 dh = (f2){DEC_HI[2 * t + 1], DEC_HI[2 * t]};
          a0 += lv[t] * dl + hv[t] * dh;
          a1 += lv[1 + t] * dl + hv[1 + t] * dh;
          a2 += lv[2 + t] * dl + hv[2 + t] * dh;
          a3 += lv[3 + t] * dl + hv[3 + t] * dh;
        }
        *reinterpret_cast<float4*>(dst + 2 * m0)     = make_float4(a0.x, a0.y, a1.x, a1.y);
        *reinterpret_cast<float4*>(dst + 2 * m0 + 4) = make_float4(a2.x, a2.y, a3.x, a3.y);
      }
    }
  }
  // s = 7: N=517, NP=512, PCH=128 = 2x64 exact (no masks)
  {
    const half_t* hsrc = ws + (size_t)row * 520;  // hi0
    float* orow = out + (size_t)row * 1024;
#pragma unroll
    for (int q0 = 0; q0 < 128; q0 += 64) {
      const int m0 = 4 * (q0 + lane);
      float lv[9];
      {
        float4 a = *reinterpret_cast<const float4*>(dst + m0);
        float4 b = *reinterpret_cast<const float4*>(dst + m0 + 4);
        lv[0] = a.x; lv[1] = a.y; lv[2] = a.z; lv[3] = a.w;
        lv[4] = b.x; lv[5] = b.y; lv[6] = b.z; lv[7] = b.w;
        lv[8] = dst[m0 + 8];
      }
      float hv[9];
      {
        h4 h0 = *reinterpret_cast<const h4*>(hsrc + m0);
        h4 h1 = *reinterpret_cast<const h4*>(hsrc + m0 + 4);
        half_t h2 = hsrc[m0 + 8];
        hv[0] = (float)h0[0]; hv[1] = (float)h0[1]; hv[2] = (float)h0[2]; hv[3] = (float)h0[3];
        hv[4] = (float)h1[0]; hv[5] = (float)h1[1]; hv[6] = (float)h1[2]; hv[7] = (float)h1[3];
        hv[8] = (float)h2;
      }
      f2 a0 = {0.f, 0.f}, a1 = {0.f, 0.f}, a2 = {0.f, 0.f}, a3 = {0.f, 0.f};
#pragma unroll
      for (int t = 0; t < 6; ++t) {
        f2 dl = (f2){DEC_LO[2 * t + 1], DEC_LO[2 * t]};
        f2 dh = (f2){DEC_HI[2 * t + 1], DEC_HI[2 * t]};
        a0 += lv[t] * dl + hv[t] * dh;
        a1 += lv[1 + t] * dl + hv[1 + t] * dh;
        a2 += lv[2 + t] * dl + hv[2 + t] * dh;
        a3 += lv[3 + t] * dl + hv[3 + t] * dh;
      }
      *reinterpret_cast<float4*>(orow + 2 * m0)     = make_float4(a0.x, a0.y, a1.x, a1.y);
      *reinterpret_cast<float4*>(orow + 2 * m0 + 4) = make_float4(a2.x, a2.y, a3.x, a3.y);
    }
  }
}

// Both einsums, 2 batches per block: blocks 0..127 -> lo mix (w1), 128..255 -> hi mix (w2).
__global__ void mix_both(half_t* __restrict__ ws, const float* __restrict__ w1,
                         const float* __restrict__ w2) {
  __shared__ float s_in[2][896];
  const int which = blockIdx.x >> 7;
  const half_t* in = ws + (size_t)NROWS * (which ? 1112 : 1128);
  const float* w = which ? w2 : w1;
  half_t* out = ws + (size_t)NROWS * (which ? 1144 : 1160);
  int b0 = (blockIdx.x & 127) * 2;
  int t = threadIdx.x;  // 896 threads; t -> (i or o = t/14, x = t%14)
  int i = t / 14, xx = t % 14;
#pragma unroll
  for (int bb = 0; bb < 2; ++bb)
    s_in[bb][t] = (float)in[((size_t)(b0 + bb) * 64 + i) * 16 + xx];
  __syncthreads();
  float acc0 = 0.f, acc1 = 0.f;
#pragma unroll 8
  for (int k = 0; k < 64; ++k) {
    float wv = w[k * 896 + t];
    acc0 += s_in[0][k * 14 + xx] * wv;
    acc1 += s_in[1][k * 14 + xx] * wv;
  }
  out[((size_t)b0 * 64 + i) * 16 + xx] = (half_t)acc0;
  out[((size_t)(b0 + 1) * 64 + i) * 16 + xx] = (half_t)acc1;
}

extern "C" void kernel_launch(void* const* d_in, const int* in_sizes, int n_in,
                              void* d_out, int out_size, void* d_ws, size_t ws_size,
                              hipStream_t stream) {
  (void)in_sizes; (void)n_in; (void)out_size; (void)ws_size;
  const float* x  = (const float*)d_in[0];
  const float* w1 = (const float*)d_in[1];
  const float* w2 = (const float*)d_in[2];
  float* out = (float*)d_out;
  half_t* ws = (half_t*)d_ws;

  afb_fused<<<NROWS / WPB, 64 * WPB, 0, stream>>>(x, ws);
  mix_both<<<256, 896, 0, stream>>>(ws, w1, w2);
  sfb_fused<<<NROWS / WPB, 64 * WPB, 0, stream>>>(ws, out);
}